// Round 6
// baseline (976.276 us; speedup 1.0000x reference)
//
#include <hip/hip_runtime.h>
#include <hip/hip_fp16.h>

#define Nn   50000
#define Ee   800000
#define IND  128
#define HIDD 64
#define OUTD 32
#define BK   64                         // nodes per bucket
#define NBK  ((Nn + BK - 1) / BK)       // 782 buckets
#define CAP  1536                       // bucket capacity (mean 1024, std 32 -> 16 sigma)
#define NCH  ((Ee + 1023) / 1024)       // 782 edge chunks (1024 edges each)
#define RB   64                         // gemm1 rows per block
#define GB   ((Nn + RB - 1) / RB)

// ---- init: zero deg + bucket cursors, detect edge dtype (block 0) ----
__global__ void k_init(const unsigned int* __restrict__ p, int* __restrict__ deg,
                       int* __restrict__ cur, int* __restrict__ flag) {
    __shared__ unsigned int red[256];
    int i = blockIdx.x * 256 + threadIdx.x;
    if (i < Nn) deg[i] = 0;
    if (i < NBK) cur[i] = 0;
    if (blockIdx.x == 0) {
        unsigned int v = 0;
        for (int k = threadIdx.x; k < 1000; k += 256) v |= p[2 * k + 1];
        red[threadIdx.x] = v;
        __syncthreads();
        for (int s = 128; s > 0; s >>= 1) {
            if (threadIdx.x < s) red[threadIdx.x] |= red[threadIdx.x + s];
            __syncthreads();
        }
        if (threadIdx.x == 0) *flag = (red[0] == 0u) ? 1 : 0;  // 1 => int64
    }
}

// ---- XCD-swizzled bucket partition + degree count ----
// block = 8*chunk + k: reads chunk's 1024 edges, keeps buckets with (b&7)==k.
// With round-robin blockIdx->XCD, each staged line is written by one XCD only.
__global__ void k_part(const void* __restrict__ p, const int* __restrict__ flag,
                       int* __restrict__ cur, int* __restrict__ deg,
                       unsigned int* __restrict__ staged) {
    int myk   = blockIdx.x & 7;
    int chunk = blockIdx.x >> 3;
    int base  = chunk * 1024 + threadIdx.x * 4;
    bool f64 = (*flag != 0);
    #pragma unroll
    for (int q = 0; q < 4; ++q) {
        int e = base + q;
        if (e >= Ee) break;
        int r, c;
        if (f64) { r = (int)((const long long*)p)[e]; c = (int)((const long long*)p)[Ee + e]; }
        else     { r = ((const int*)p)[e];            c = ((const int*)p)[Ee + e]; }
        int b = c >> 6;
        if ((b & 7) == myk) {
            atomicAdd(&deg[c], 1);                       // no-return, fire-and-forget
            int pos = atomicAdd(&cur[b], 1);
            if (pos < CAP)
                staged[(size_t)b * CAP + pos] = ((unsigned int)(c & 63) << 16) | (unsigned int)r;
        }
    }
}

__global__ void k_dis(const int* __restrict__ deg, float* __restrict__ dis) {
    int i = blockIdx.x * 256 + threadIdx.x;
    if (i < Nn) dis[i] = rsqrtf((float)deg[i] + 1.0f);
}

// ---- GEMM1: 4x4 register tiles, 64 rows/block, fp16 output (unchanged) ----
__global__ __launch_bounds__(256) void k_gemm1(const float* __restrict__ x,
                                               const float* __restrict__ W,
                                               __half* __restrict__ h) {
    __shared__ float xs[RB][IND + 4];
    __shared__ float Ws[IND * HIDD];
    int t = threadIdx.x;
    int row0 = blockIdx.x * RB;
    for (int i = t; i < IND * HIDD / 4; i += 256)
        ((float4*)Ws)[i] = ((const float4*)W)[i];
    for (int i = t; i < RB * IND / 4; i += 256) {
        int rr = i >> 5, cc = (i & 31) * 4;
        int gr = row0 + rr;
        float4 v = make_float4(0.f, 0.f, 0.f, 0.f);
        if (gr < Nn) v = ((const float4*)x)[(size_t)gr * (IND / 4) + (i & 31)];
        *(float4*)&xs[rr][cc] = v;
    }
    __syncthreads();
    int jg = t & 15, rg = t >> 4;
    float acc[4][4] = {{0.f,0.f,0.f,0.f},{0.f,0.f,0.f,0.f},
                       {0.f,0.f,0.f,0.f},{0.f,0.f,0.f,0.f}};
    for (int k = 0; k < IND; k += 4) {
        float4 xv0 = *(const float4*)&xs[rg * 4 + 0][k];
        float4 xv1 = *(const float4*)&xs[rg * 4 + 1][k];
        float4 xv2 = *(const float4*)&xs[rg * 4 + 2][k];
        float4 xv3 = *(const float4*)&xs[rg * 4 + 3][k];
        float4 w0 = *(const float4*)&Ws[(k + 0) * HIDD + jg * 4];
        float4 w1 = *(const float4*)&Ws[(k + 1) * HIDD + jg * 4];
        float4 w2 = *(const float4*)&Ws[(k + 2) * HIDD + jg * 4];
        float4 w3 = *(const float4*)&Ws[(k + 3) * HIDD + jg * 4];
        #define ROWSTEP(XV, R) \
            acc[R][0]=fmaf(XV.x,w0.x,acc[R][0]); acc[R][1]=fmaf(XV.x,w0.y,acc[R][1]); \
            acc[R][2]=fmaf(XV.x,w0.z,acc[R][2]); acc[R][3]=fmaf(XV.x,w0.w,acc[R][3]); \
            acc[R][0]=fmaf(XV.y,w1.x,acc[R][0]); acc[R][1]=fmaf(XV.y,w1.y,acc[R][1]); \
            acc[R][2]=fmaf(XV.y,w1.z,acc[R][2]); acc[R][3]=fmaf(XV.y,w1.w,acc[R][3]); \
            acc[R][0]=fmaf(XV.z,w2.x,acc[R][0]); acc[R][1]=fmaf(XV.z,w2.y,acc[R][1]); \
            acc[R][2]=fmaf(XV.z,w2.z,acc[R][2]); acc[R][3]=fmaf(XV.z,w2.w,acc[R][3]); \
            acc[R][0]=fmaf(XV.w,w3.x,acc[R][0]); acc[R][1]=fmaf(XV.w,w3.y,acc[R][1]); \
            acc[R][2]=fmaf(XV.w,w3.z,acc[R][2]); acc[R][3]=fmaf(XV.w,w3.w,acc[R][3]);
        ROWSTEP(xv0, 0) ROWSTEP(xv1, 1) ROWSTEP(xv2, 2) ROWSTEP(xv3, 3)
        #undef ROWSTEP
    }
    #pragma unroll
    for (int rr = 0; rr < 4; ++rr) {
        int gr = row0 + rg * 4 + rr;
        if (gr < Nn) {
            __half2 lo = __floats2half2_rn(acc[rr][0], acc[rr][1]);
            __half2 hi = __floats2half2_rn(acc[rr][2], acc[rr][3]);
            uint2 pk = make_uint2(*(unsigned int*)&lo, *(unsigned int*)&hi);
            *(uint2*)&h[(size_t)gr * HIDD + jg * 4] = pk;
        }
    }
}

// ---- layer-1 agg (LDS accumulate) + bias/self/ReLU + fused GEMM2 ----
// one block per 64-node bucket; 8 groups x 32 lanes; half2 feature pairs
__global__ __launch_bounds__(256) void k_agg1(const unsigned int* __restrict__ staged,
        const int* __restrict__ cur, const float* __restrict__ dis,
        const __half2* __restrict__ h1v, const __half* __restrict__ h1s,
        const float* __restrict__ b1, const float* __restrict__ W2,
        __half* __restrict__ h2) {
    __shared__ float acc[BK][HIDD];         // 16 KB
    __shared__ float W2t[OUTD][HIDD + 4];   // transposed+padded, 8.5 KB
    int t = threadIdx.x, b = blockIdx.x;
    for (int i = t; i < HIDD * OUTD; i += 256) W2t[i & 31][i >> 5] = W2[i];
    for (int i = t; i < BK * HIDD / 4; i += 256) ((float4*)acc)[i] = make_float4(0.f,0.f,0.f,0.f);
    __syncthreads();
    int m = cur[b]; if (m > CAP) m = CAP;
    const unsigned int* sp = staged + (size_t)b * CAP;
    int g = t >> 5, lane = t & 31;
    int i = g;
    for (; i + 24 < m; i += 32) {
        unsigned int v0 = sp[i], v1 = sp[i + 8], v2 = sp[i + 16], v3 = sp[i + 24];
        int r0 = v0 & 0xFFFF, c0 = v0 >> 16;
        int r1 = v1 & 0xFFFF, c1 = v1 >> 16;
        int r2 = v2 & 0xFFFF, c2 = v2 >> 16;
        int r3 = v3 & 0xFFFF, c3 = v3 >> 16;
        float n0 = dis[r0], n1 = dis[r1], n2 = dis[r2], n3 = dis[r3];
        float2 f0 = __half22float2(h1v[(size_t)r0 * 32 + lane]);
        float2 f1 = __half22float2(h1v[(size_t)r1 * 32 + lane]);
        float2 f2 = __half22float2(h1v[(size_t)r2 * 32 + lane]);
        float2 f3 = __half22float2(h1v[(size_t)r3 * 32 + lane]);
        atomicAdd(&acc[c0][2 * lane], n0 * f0.x); atomicAdd(&acc[c0][2 * lane + 1], n0 * f0.y);
        atomicAdd(&acc[c1][2 * lane], n1 * f1.x); atomicAdd(&acc[c1][2 * lane + 1], n1 * f1.y);
        atomicAdd(&acc[c2][2 * lane], n2 * f2.x); atomicAdd(&acc[c2][2 * lane + 1], n2 * f2.y);
        atomicAdd(&acc[c3][2 * lane], n3 * f3.x); atomicAdd(&acc[c3][2 * lane + 1], n3 * f3.y);
    }
    for (; i < m; i += 8) {
        unsigned int v0 = sp[i];
        int r0 = v0 & 0xFFFF, c0 = v0 >> 16;
        float n0 = dis[r0];
        float2 f0 = __half22float2(h1v[(size_t)r0 * 32 + lane]);
        atomicAdd(&acc[c0][2 * lane], n0 * f0.x); atomicAdd(&acc[c0][2 * lane + 1], n0 * f0.y);
    }
    __syncthreads();
    // epilogue: agg = dis[n]*acc + b1 + dis[n]^2*self; relu in place
    for (int ii = t; ii < BK * HIDD; ii += 256) {
        int nl = ii >> 6, j = ii & 63;
        int n = b * BK + nl;
        float v = 0.f;
        if (n < Nn) {
            float d = dis[n];
            v = d * acc[nl][j] + b1[j] + d * d * __half2float(h1s[(size_t)n * HIDD + j]);
            v = fmaxf(v, 0.f);
        }
        acc[nl][j] = v;
    }
    __syncthreads();
    // gemm2: thread t -> node nl=t/4, outputs j0..j0+7
    int nl = t >> 2, j0 = (t & 3) * 8;
    float o[8] = {0,0,0,0,0,0,0,0};
    const float4* ar = (const float4*)acc[nl];
    #pragma unroll
    for (int kk = 0; kk < HIDD / 4; ++kk) {
        float4 a4 = ar[kk];
        #pragma unroll
        for (int q = 0; q < 8; ++q) {
            float4 w4 = *(const float4*)&W2t[j0 + q][kk * 4];
            o[q] = fmaf(a4.x, w4.x, o[q]); o[q] = fmaf(a4.y, w4.y, o[q]);
            o[q] = fmaf(a4.z, w4.z, o[q]); o[q] = fmaf(a4.w, w4.w, o[q]);
        }
    }
    int n = b * BK + nl;
    if (n < Nn) {
        __half hs[8];
        #pragma unroll
        for (int q = 0; q < 8; ++q) hs[q] = __float2half(o[q]);
        *(uint4*)&h2[(size_t)n * OUTD + j0] = *(uint4*)hs;
    }
}

// ---- layer-2 agg: 16 groups x 16 lanes; writes final fp32 output ----
__global__ __launch_bounds__(256) void k_agg2(const unsigned int* __restrict__ staged,
        const int* __restrict__ cur, const float* __restrict__ dis,
        const __half2* __restrict__ h2v, const __half* __restrict__ h2s,
        const float* __restrict__ b2, float* __restrict__ out) {
    __shared__ float acc[BK][OUTD];   // 8 KB
    int t = threadIdx.x, b = blockIdx.x;
    for (int i = t; i < BK * OUTD / 4; i += 256) ((float4*)acc)[i] = make_float4(0.f,0.f,0.f,0.f);
    __syncthreads();
    int m = cur[b]; if (m > CAP) m = CAP;
    const unsigned int* sp = staged + (size_t)b * CAP;
    int g = t >> 4, lane = t & 15;
    int i = g;
    for (; i + 48 < m; i += 64) {
        unsigned int v0 = sp[i], v1 = sp[i + 16], v2 = sp[i + 32], v3 = sp[i + 48];
        int r0 = v0 & 0xFFFF, c0 = v0 >> 16;
        int r1 = v1 & 0xFFFF, c1 = v1 >> 16;
        int r2 = v2 & 0xFFFF, c2 = v2 >> 16;
        int r3 = v3 & 0xFFFF, c3 = v3 >> 16;
        float n0 = dis[r0], n1 = dis[r1], n2 = dis[r2], n3 = dis[r3];
        float2 f0 = __half22float2(h2v[(size_t)r0 * 16 + lane]);
        float2 f1 = __half22float2(h2v[(size_t)r1 * 16 + lane]);
        float2 f2 = __half22float2(h2v[(size_t)r2 * 16 + lane]);
        float2 f3 = __half22float2(h2v[(size_t)r3 * 16 + lane]);
        atomicAdd(&acc[c0][2 * lane], n0 * f0.x); atomicAdd(&acc[c0][2 * lane + 1], n0 * f0.y);
        atomicAdd(&acc[c1][2 * lane], n1 * f1.x); atomicAdd(&acc[c1][2 * lane + 1], n1 * f1.y);
        atomicAdd(&acc[c2][2 * lane], n2 * f2.x); atomicAdd(&acc[c2][2 * lane + 1], n2 * f2.y);
        atomicAdd(&acc[c3][2 * lane], n3 * f3.x); atomicAdd(&acc[c3][2 * lane + 1], n3 * f3.y);
    }
    for (; i < m; i += 16) {
        unsigned int v0 = sp[i];
        int r0 = v0 & 0xFFFF, c0 = v0 >> 16;
        float n0 = dis[r0];
        float2 f0 = __half22float2(h2v[(size_t)r0 * 16 + lane]);
        atomicAdd(&acc[c0][2 * lane], n0 * f0.x); atomicAdd(&acc[c0][2 * lane + 1], n0 * f0.y);
    }
    __syncthreads();
    for (int ii = t; ii < BK * OUTD; ii += 256) {
        int nl = ii >> 5, j = ii & 31;
        int n = b * BK + nl;
        if (n < Nn) {
            float d = dis[n];
            out[(size_t)n * OUTD + j] =
                d * acc[nl][j] + b2[j] + d * d * __half2float(h2s[(size_t)n * OUTD + j]);
        }
    }
}

extern "C" void kernel_launch(void* const* d_in, const int* in_sizes, int n_in,
                              void* d_out, int out_size, void* d_ws, size_t ws_size,
                              hipStream_t stream) {
    const float* x  = (const float*)d_in[0];
    const void*  ei = d_in[1];
    const float* W1 = (const float*)d_in[2];
    const float* b1 = (const float*)d_in[3];
    const float* W2 = (const float*)d_in[4];
    const float* b2 = (const float*)d_in[5];
    float* out = (float*)d_out;

    char* w = (char*)d_ws;
    int*          flag   = (int*)w;          w += 256;
    int*          deg    = (int*)w;          w += (size_t)Nn * 4;
    int*          cur    = (int*)w;          w += ((size_t)NBK * 4 + 255) / 256 * 256;
    float*        dis    = (float*)w;        w += (size_t)Nn * 4;
    unsigned int* staged = (unsigned int*)w; w += (size_t)NBK * CAP * 4;   // 4.8 MB
    __half*       h1     = (__half*)w;       w += (size_t)Nn * HIDD * 2;   // 6.4 MB
    __half*       h2     = (__half*)w;       w += (size_t)Nn * OUTD * 2;   // 3.2 MB

    k_init <<<(Nn + 255) / 256, 256, 0, stream>>>((const unsigned int*)ei, deg, cur, flag);
    k_part <<<NCH * 8, 256, 0, stream>>>(ei, flag, cur, deg, staged);
    k_dis  <<<(Nn + 255) / 256, 256, 0, stream>>>(deg, dis);
    k_gemm1<<<GB, 256, 0, stream>>>(x, W1, h1);
    k_agg1 <<<NBK, 256, 0, stream>>>(staged, cur, dis, (const __half2*)h1, h1, b1, W2, h2);
    k_agg2 <<<NBK, 256, 0, stream>>>(staged, cur, dis, (const __half2*)h2, h2, b2, out);
}

// Round 7
// 236.864 us; speedup vs baseline: 4.1217x; 4.1217x over previous
//
#include <hip/hip_runtime.h>
#include <hip/hip_fp16.h>

#define Nn   50000
#define Ee   800000
#define IND  128
#define HIDD 64
#define OUTD 32
#define NB1  ((Nn + 255) / 256)        // 196
#define CB   ((Ee / 4 + 255) / 256)    // 782 blocks, 4 edges/thread
#define NCH  ((Ee + 1023) / 1024)      // 782 chunks of 1024 edges
#define RB   64                        // gemm1 rows per block
#define GB   ((Nn + RB - 1) / RB)

// ---- init: zero cnt + edge dtype detection (block 0) ----
__global__ void k_init(const unsigned int* __restrict__ p, int* __restrict__ cnt,
                       int* __restrict__ flag) {
    __shared__ unsigned int red[256];
    int i = blockIdx.x * 256 + threadIdx.x;
    if (i < Nn) cnt[i] = 0;
    if (blockIdx.x == 0) {
        unsigned int v = 0;
        for (int k = threadIdx.x; k < 1000; k += 256) v |= p[2 * k + 1];
        red[threadIdx.x] = v;
        __syncthreads();
        for (int s = 128; s > 0; s >>= 1) {
            if (threadIdx.x < s) red[threadIdx.x] |= red[threadIdx.x + s];
            __syncthreads();
        }
        if (threadIdx.x == 0) *flag = (red[0] == 0u) ? 1 : 0;  // 1 => int64
    }
}

// ---- in-degree count, 4 edges/thread ----
__global__ void k_count(const void* __restrict__ p, const int* __restrict__ flag,
                        int* __restrict__ cnt) {
    int base = (blockIdx.x * 256 + threadIdx.x) * 4;
    bool f64 = (*flag != 0);
    #pragma unroll
    for (int q = 0; q < 4; ++q) {
        int e = base + q;
        if (e >= Ee) return;
        int c = f64 ? (int)((const long long*)p)[Ee + e] : ((const int*)p)[Ee + e];
        atomicAdd(&cnt[c], 1);
    }
}

// ---- hierarchical exclusive scan (dis fused into pass 1) ----
__global__ void k_scan1(const int* __restrict__ cnt, int* __restrict__ scanned,
                        int* __restrict__ bsum, float* __restrict__ dis) {
    __shared__ int sh[256];
    int b = blockIdx.x, t = threadIdx.x, i = b * 256 + t;
    int v = (i < Nn) ? cnt[i] : 0;
    if (i < Nn) dis[i] = rsqrtf((float)v + 1.0f);  // +1 self-loop
    sh[t] = v;
    __syncthreads();
    for (int off = 1; off < 256; off <<= 1) {
        int add = (t >= off) ? sh[t - off] : 0;
        __syncthreads();
        sh[t] += add;
        __syncthreads();
    }
    if (i < Nn) scanned[i] = sh[t] - v;
    if (t == 255) bsum[b] = sh[255];
}

__global__ void k_scan2(int* __restrict__ bsum) {
    __shared__ int sh[256];
    int t = threadIdx.x;
    int v = (t < NB1) ? bsum[t] : 0;
    sh[t] = v;
    __syncthreads();
    for (int off = 1; off < 256; off <<= 1) {
        int add = (t >= off) ? sh[t - off] : 0;
        __syncthreads();
        sh[t] += add;
        __syncthreads();
    }
    if (t < NB1) bsum[t] = sh[t] - v;
}

__global__ void k_scan3(const int* __restrict__ scanned, const int* __restrict__ bsum,
                        int* __restrict__ rowstart, int* __restrict__ cursor) {
    int i = blockIdx.x * 256 + threadIdx.x;
    if (i < Nn) {
        rowstart[i] = scanned[i] + bsum[blockIdx.x];
        cursor[i] = 0;
    }
    if (i == 0) rowstart[Nn] = Ee;
}

// ---- GEMM1: 4x4 register tiles, 64 rows/block, fp16 output ----
__global__ __launch_bounds__(256) void k_gemm1(const float* __restrict__ x,
                                               const float* __restrict__ W,
                                               __half* __restrict__ h) {
    __shared__ float xs[RB][IND + 4];
    __shared__ float Ws[IND * HIDD];
    int t = threadIdx.x;
    int row0 = blockIdx.x * RB;
    for (int i = t; i < IND * HIDD / 4; i += 256)
        ((float4*)Ws)[i] = ((const float4*)W)[i];
    for (int i = t; i < RB * IND / 4; i += 256) {
        int rr = i >> 5, cc = (i & 31) * 4;
        int gr = row0 + rr;
        float4 v = make_float4(0.f, 0.f, 0.f, 0.f);
        if (gr < Nn) v = ((const float4*)x)[(size_t)gr * (IND / 4) + (i & 31)];
        *(float4*)&xs[rr][cc] = v;
    }
    __syncthreads();
    int jg = t & 15, rg = t >> 4;
    float acc[4][4] = {{0.f,0.f,0.f,0.f},{0.f,0.f,0.f,0.f},
                       {0.f,0.f,0.f,0.f},{0.f,0.f,0.f,0.f}};
    for (int k = 0; k < IND; k += 4) {
        float4 xv0 = *(const float4*)&xs[rg * 4 + 0][k];
        float4 xv1 = *(const float4*)&xs[rg * 4 + 1][k];
        float4 xv2 = *(const float4*)&xs[rg * 4 + 2][k];
        float4 xv3 = *(const float4*)&xs[rg * 4 + 3][k];
        float4 w0 = *(const float4*)&Ws[(k + 0) * HIDD + jg * 4];
        float4 w1 = *(const float4*)&Ws[(k + 1) * HIDD + jg * 4];
        float4 w2 = *(const float4*)&Ws[(k + 2) * HIDD + jg * 4];
        float4 w3 = *(const float4*)&Ws[(k + 3) * HIDD + jg * 4];
        #define ROWSTEP(XV, R) \
            acc[R][0]=fmaf(XV.x,w0.x,acc[R][0]); acc[R][1]=fmaf(XV.x,w0.y,acc[R][1]); \
            acc[R][2]=fmaf(XV.x,w0.z,acc[R][2]); acc[R][3]=fmaf(XV.x,w0.w,acc[R][3]); \
            acc[R][0]=fmaf(XV.y,w1.x,acc[R][0]); acc[R][1]=fmaf(XV.y,w1.y,acc[R][1]); \
            acc[R][2]=fmaf(XV.y,w1.z,acc[R][2]); acc[R][3]=fmaf(XV.y,w1.w,acc[R][3]); \
            acc[R][0]=fmaf(XV.z,w2.x,acc[R][0]); acc[R][1]=fmaf(XV.z,w2.y,acc[R][1]); \
            acc[R][2]=fmaf(XV.z,w2.z,acc[R][2]); acc[R][3]=fmaf(XV.z,w2.w,acc[R][3]); \
            acc[R][0]=fmaf(XV.w,w3.x,acc[R][0]); acc[R][1]=fmaf(XV.w,w3.y,acc[R][1]); \
            acc[R][2]=fmaf(XV.w,w3.z,acc[R][2]); acc[R][3]=fmaf(XV.w,w3.w,acc[R][3]);
        ROWSTEP(xv0, 0) ROWSTEP(xv1, 1) ROWSTEP(xv2, 2) ROWSTEP(xv3, 3)
        #undef ROWSTEP
    }
    #pragma unroll
    for (int rr = 0; rr < 4; ++rr) {
        int gr = row0 + rg * 4 + rr;
        if (gr < Nn) {
            __half2 lo = __floats2half2_rn(acc[rr][0], acc[rr][1]);
            __half2 hi = __floats2half2_rn(acc[rr][2], acc[rr][3]);
            uint2 pk = make_uint2(*(unsigned int*)&lo, *(unsigned int*)&hi);
            *(uint2*)&h[(size_t)gr * HIDD + jg * 4] = pk;
        }
    }
}

// ---- scatter: XCD-filtered 8-pass, packed 4B slots {half(dis[row])<<16 | row} ----
// block = 8*chunk + k processes chunk's 1024 edges, keeps (c>>6)&7 == k.
// All writers of a 64-node run-region land on one XCD -> lines fill in one L2.
__global__ void k_scatter(const void* __restrict__ p, const int* __restrict__ flag,
                          const float* __restrict__ dis, const int* __restrict__ rowstart,
                          int* __restrict__ cursor, unsigned int* __restrict__ slots) {
    int myk   = blockIdx.x & 7;
    int chunk = blockIdx.x >> 3;
    int base  = chunk * 1024 + threadIdx.x * 4;
    bool f64 = (*flag != 0);
    #pragma unroll
    for (int q = 0; q < 4; ++q) {
        int e = base + q;
        if (e >= Ee) break;
        int c = f64 ? (int)((const long long*)p)[Ee + e] : ((const int*)p)[Ee + e];
        if (((c >> 6) & 7) != myk) continue;
        int r = f64 ? (int)((const long long*)p)[e] : ((const int*)p)[e];
        unsigned int sl = ((unsigned int)__half_as_ushort(__float2half(dis[r])) << 16)
                        | (unsigned int)r;
        int pos = rowstart[c] + atomicAdd(&cursor[c], 1);
        slots[pos] = sl;
    }
}

// ---- layer-1 aggregation + fused GEMM2: 8 nodes/block, 32 lanes/node, MLP=8 ----
__global__ __launch_bounds__(256) void k_agg1(const unsigned int* __restrict__ slots,
        const int* __restrict__ rowstart, const float* __restrict__ dis,
        const __half2* __restrict__ h1, const float* __restrict__ b1,
        const float* __restrict__ W2, __half* __restrict__ h2) {
    __shared__ float sh[8][HIDD];      // 2 KB
    __shared__ float W2s[HIDD * OUTD]; // 8 KB
    int t = threadIdx.x;
    for (int i = t; i < HIDD * OUTD; i += 256) W2s[i] = W2[i];
    int sub = t >> 5, lane = t & 31;
    int n = blockIdx.x * 8 + sub;
    int s = rowstart[n], e = rowstart[n + 1];
    float d = dis[n];
    float2 self = __half22float2(h1[n * 32 + lane]);
    float2 acc = make_float2(b1[2 * lane]     + d * d * self.x,
                             b1[2 * lane + 1] + d * d * self.y);
    int p = s;
    for (; p + 8 <= e; p += 8) {
        unsigned int sv[8];
        #pragma unroll
        for (int q = 0; q < 8; ++q) sv[q] = slots[p + q];
        float2 fv[8];
        #pragma unroll
        for (int q = 0; q < 8; ++q)
            fv[q] = __half22float2(h1[(sv[q] & 0xFFFFu) * 32 + lane]);
        #pragma unroll
        for (int q = 0; q < 8; ++q) {
            float nr = d * __half2float(__ushort_as_half((unsigned short)(sv[q] >> 16)));
            acc.x = fmaf(nr, fv[q].x, acc.x); acc.y = fmaf(nr, fv[q].y, acc.y);
        }
    }
    for (; p < e; ++p) {
        unsigned int s0 = slots[p];
        float2 v = __half22float2(h1[(s0 & 0xFFFFu) * 32 + lane]);
        float nr = d * __half2float(__ushort_as_half((unsigned short)(s0 >> 16)));
        acc.x = fmaf(nr, v.x, acc.x); acc.y = fmaf(nr, v.y, acc.y);
    }
    sh[sub][2 * lane]     = fmaxf(acc.x, 0.0f);
    sh[sub][2 * lane + 1] = fmaxf(acc.y, 0.0f);
    __syncthreads();
    int jn = t >> 5, j = t & 31;
    float o = 0.0f;
    #pragma unroll
    for (int k = 0; k < HIDD; ++k) o = fmaf(sh[jn][k], W2s[k * OUTD + j], o);
    h2[(blockIdx.x * 8 + jn) * OUTD + j] = __float2half(o);
}

// ---- layer-2 aggregation: 16 nodes/block, 16 lanes/node, MLP=8 ----
__global__ __launch_bounds__(256) void k_agg2(const unsigned int* __restrict__ slots,
        const int* __restrict__ rowstart, const float* __restrict__ dis,
        const __half2* __restrict__ h2, const float* __restrict__ b2,
        float* __restrict__ out) {
    int t = threadIdx.x;
    int sub = t >> 4, lane = t & 15;
    int n = blockIdx.x * 16 + sub;
    int s = rowstart[n], e = rowstart[n + 1];
    float d = dis[n];
    float2 self = __half22float2(h2[n * 16 + lane]);
    float2 acc = make_float2(b2[2 * lane]     + d * d * self.x,
                             b2[2 * lane + 1] + d * d * self.y);
    int p = s;
    for (; p + 8 <= e; p += 8) {
        unsigned int sv[8];
        #pragma unroll
        for (int q = 0; q < 8; ++q) sv[q] = slots[p + q];
        float2 fv[8];
        #pragma unroll
        for (int q = 0; q < 8; ++q)
            fv[q] = __half22float2(h2[(sv[q] & 0xFFFFu) * 16 + lane]);
        #pragma unroll
        for (int q = 0; q < 8; ++q) {
            float nr = d * __half2float(__ushort_as_half((unsigned short)(sv[q] >> 16)));
            acc.x = fmaf(nr, fv[q].x, acc.x); acc.y = fmaf(nr, fv[q].y, acc.y);
        }
    }
    for (; p < e; ++p) {
        unsigned int s0 = slots[p];
        float2 v = __half22float2(h2[(s0 & 0xFFFFu) * 16 + lane]);
        float nr = d * __half2float(__ushort_as_half((unsigned short)(s0 >> 16)));
        acc.x = fmaf(nr, v.x, acc.x); acc.y = fmaf(nr, v.y, acc.y);
    }
    ((float2*)out)[n * 16 + lane] = acc;
}

extern "C" void kernel_launch(void* const* d_in, const int* in_sizes, int n_in,
                              void* d_out, int out_size, void* d_ws, size_t ws_size,
                              hipStream_t stream) {
    const float* x  = (const float*)d_in[0];
    const void*  ei = d_in[1];
    const float* W1 = (const float*)d_in[2];
    const float* b1 = (const float*)d_in[3];
    const float* W2 = (const float*)d_in[4];
    const float* b2 = (const float*)d_in[5];
    float* out = (float*)d_out;

    char* w = (char*)d_ws;
    int*          flag     = (int*)w;          w += 256;
    int*          cnt      = (int*)w;          w += (size_t)Nn * 4;      // reused as cursor
    int*          scanned  = (int*)w;          w += (size_t)Nn * 4;
    int*          bsum     = (int*)w;          w += (size_t)NB1 * 4 + 240;
    int*          rowstart = (int*)w;          w += (size_t)(Nn + 1) * 4 + 188;
    float*        dis      = (float*)w;        w += (size_t)Nn * 4;
    unsigned int* slots    = (unsigned int*)w; w += (size_t)Ee * 4;        // 3.2 MB
    __half*       h1       = (__half*)w;       w += (size_t)Nn * HIDD * 2; // 6.4 MB
    __half*       h2       = (__half*)w;       w += (size_t)Nn * OUTD * 2; // 3.2 MB

    k_init   <<<NB1, 256, 0, stream>>>((const unsigned int*)ei, cnt, flag);
    k_count  <<<CB, 256, 0, stream>>>(ei, flag, cnt);
    k_scan1  <<<NB1, 256, 0, stream>>>(cnt, scanned, bsum, dis);
    k_scan2  <<<1, 256, 0, stream>>>(bsum);
    k_scan3  <<<NB1, 256, 0, stream>>>(scanned, bsum, rowstart, cnt);  // cnt -> cursor=0
    k_gemm1  <<<GB, 256, 0, stream>>>(x, W1, h1);
    k_scatter<<<NCH * 8, 256, 0, stream>>>(ei, flag, dis, rowstart, cnt, slots);
    k_agg1   <<<Nn / 8, 256, 0, stream>>>(slots, rowstart, dis, (const __half2*)h1, b1, W2, h2);
    k_agg2   <<<Nn / 16, 256, 0, stream>>>(slots, rowstart, dis, (const __half2*)h2, b2, out);
}